// Round 16
// baseline (225.002 us; speedup 1.0000x reference)
//
#include <hip/hip_runtime.h>

typedef __attribute__((ext_vector_type(4)))  float    f32x4;
typedef __attribute__((ext_vector_type(16))) float    f32x16;
typedef __attribute__((ext_vector_type(8)))  short    bf16x8;
typedef __attribute__((ext_vector_type(8)))  _Float16 f16x8;
typedef __attribute__((ext_vector_type(4)))  _Float16 f16x4;
typedef __attribute__((ext_vector_type(4)))  unsigned uint4v;
typedef __fp16 h2 __attribute__((ext_vector_type(2)));

// ---------- helpers ----------
__device__ inline unsigned pkrtz(float a, float b) {
    auto v = __builtin_amdgcn_cvt_pkrtz(a, b);
    return __builtin_bit_cast(unsigned, v);
}
// raw v_exp_f32: safe here (|arg| <= 11.6 -> fully normal range, ~1 ULP)
__device__ inline float fexp2(float x) {
#if __has_builtin(__builtin_amdgcn_exp2f)
    return __builtin_amdgcn_exp2f(x);
#else
    return exp2f(x);
#endif
}
__device__ inline void gld16(void* lds, const void* g) {
    __builtin_amdgcn_global_load_lds(
        (const __attribute__((address_space(1))) void*)g,
        (__attribute__((address_space(3))) void*)lds, 16, 0, 0);
}

// half-exchange across the wave's 32-lane halves (hazard-safe builtin path;
// raw asm version produced sporadic stale reads in R6).
__device__ inline void half_exchange(unsigned& a0, unsigned& a1,
                                     unsigned& b0, unsigned& b1, int g2) {
#if __has_builtin(__builtin_amdgcn_permlane32_swap)
    {
        auto p = __builtin_amdgcn_permlane32_swap(a0, b0, false, false);
        a0 = p[0]; b0 = p[1];
        auto q = __builtin_amdgcn_permlane32_swap(a1, b1, false, false);
        a1 = q[0]; b1 = q[1];
    }
#else
    unsigned s0 = g2 ? a0 : b0, s1 = g2 ? a1 : b1;
    unsigned r0 = (unsigned)__shfl_xor((int)s0, 32);
    unsigned r1 = (unsigned)__shfl_xor((int)s1, 32);
    unsigned w0 = g2 ? r0 : a0, w1 = g2 ? r1 : a1;
    unsigned w2 = g2 ? b0 : r0, w3 = g2 ? b1 : r1;
    a0 = w0; a1 = w1; b0 = w2; b1 = w3;
#endif
}

// ---------------------------------------------------------------------------
// fused prep: x,wq,wk,wv,wo -> f16 (all GEMM inputs f16 single-MFMA).
// ---------------------------------------------------------------------------
__global__ __launch_bounds__(256) void split_all(
    const float* __restrict__ x,  const float* __restrict__ wq,
    const float* __restrict__ wk, const float* __restrict__ wv,
    const float* __restrict__ wo,
    _Float16* __restrict__ Xf, _Float16* __restrict__ Wqkvf,
    _Float16* __restrict__ Wof)
{
    const int b = blockIdx.x;
    const float* s; _Float16* d; int i;
    if (b < 2400)      { s = x;  d = Xf;                  i = b * 256 + threadIdx.x; }
    else if (b < 2912) { s = wq; d = Wqkvf;               i = (b - 2400) * 256 + threadIdx.x; }
    else if (b < 3424) { s = wk; d = Wqkvf + 1024 * 1024; i = (b - 2912) * 256 + threadIdx.x; }
    else if (b < 3936) { s = wv; d = Wqkvf + 2048 * 1024; i = (b - 3424) * 256 + threadIdx.x; }
    else               { s = wo; d = Wof;                 i = (b - 3936) * 256 + threadIdx.x; }

    f32x4 a = ((const f32x4*)s)[2 * i];
    f32x4 c = ((const f32x4*)s)[2 * i + 1];
    f16x8 v;
#pragma unroll
    for (int j = 0; j < 4; j++) { v[j] = (_Float16)a[j]; v[4 + j] = (_Float16)c[j]; }
    ((f16x8*)d)[i] = v;
}

// ---------------------------------------------------------------------------
// Fused QKV GEMM (128x128x32, single f16 MFMA) + RMSNorm/RoPE/f16 epilogue.
// ---------------------------------------------------------------------------
__global__ __launch_bounds__(256) void gemm_qkv(
    const _Float16* __restrict__ Af, const _Float16* __restrict__ Bf,
    const float* __restrict__ rope,
    const float* __restrict__ qgam, const float* __restrict__ kgam,
    _Float16* __restrict__ Qh, _Float16* __restrict__ Kh,
    _Float16* __restrict__ Vt)
{
    __shared__ _Float16 sA[128 * 32], sB[128 * 32];

    const int tid = threadIdx.x, lane = tid & 63, wv = tid >> 6;
    const int wm = wv >> 1, wn = wv & 1;
    const int r = lane & 15, g = lane >> 4;
    const int m0 = blockIdx.y * 128, n0 = blockIdx.x * 128;
    const int K = 1024, L = 4800;

    const int c0 = tid, c1 = tid + 256;
    const int ar0 = c0 >> 2, ac0 = ((c0 & 3) ^ (ar0 & 3)) * 8;
    const int ar1 = c1 >> 2, ac1 = ((c1 & 3) ^ (ar1 & 3)) * 8;
    const size_t offA0 = (size_t)(m0 + ar0) * K + ac0;
    const size_t offA1 = (size_t)(m0 + ar1) * K + ac1;
    const size_t offB0 = (size_t)(n0 + ar0) * K + ac0;
    const size_t offB1 = (size_t)(n0 + ar1) * K + ac1;
    const int d0 = tid * 16, d1 = (tid + 256) * 16;

    f32x4 acc[4][4];
#pragma unroll
    for (int mf = 0; mf < 4; mf++)
#pragma unroll
        for (int nf = 0; nf < 4; nf++)
            acc[mf][nf] = (f32x4){0.f, 0.f, 0.f, 0.f};

    for (int kk = 0; kk < K; kk += 32) {
        __syncthreads();
        gld16((char*)sA + d0, Af + offA0 + kk);
        gld16((char*)sA + d1, Af + offA1 + kk);
        gld16((char*)sB + d0, Bf + offB0 + kk);
        gld16((char*)sB + d1, Bf + offB1 + kk);
        __syncthreads();

        f16x8 fb[4];
#pragma unroll
        for (int nf = 0; nf < 4; nf++) {
            int row = wn * 64 + nf * 16 + r;
            fb[nf] = *(const f16x8*)((const char*)sB + row * 64 + ((g ^ (row & 3)) * 16));
        }
#pragma unroll
        for (int mf = 0; mf < 4; mf++) {
            int row = wm * 64 + mf * 16 + r;
            f16x8 fa = *(const f16x8*)((const char*)sA + row * 64 + ((g ^ (row & 3)) * 16));
#pragma unroll
            for (int nf = 0; nf < 4; nf++)
                acc[mf][nf] = __builtin_amdgcn_mfma_f32_16x16x32_f16(fa, fb[nf], acc[mf][nf], 0, 0, 0);
        }
    }

    // ---------------- fused epilogue ----------------
    const int col0  = n0 + wn * 64;
    const int which = col0 >> 10;          // 0=Q 1=K 2=V
    const int hd    = (col0 & 1023) >> 6;  // head 0..15

    if (which == 2) {
#pragma unroll
        for (int mf = 0; mf < 4; mf++) {
            const int l0 = m0 + wm * 64 + mf * 16 + 4 * g;
            if (l0 < L) {
#pragma unroll
                for (int nf = 0; nf < 4; nf++) {
                    f16x4 v4;
#pragma unroll
                    for (int e = 0; e < 4; e++) v4[e] = (_Float16)acc[mf][nf][e];
                    *(f16x4*)(Vt + (size_t)(hd * 64 + nf * 16 + r) * L + l0) = v4;
                }
            }
        }
        return;
    }

    const float* G = which ? kgam : qgam;
    const float qs = which ? 1.0f : 0.18033688011112042f; // (1/8)*log2(e)
    float gam[4];
#pragma unroll
    for (int nf = 0; nf < 4; nf++) gam[nf] = G[nf * 16 + r];
    _Float16* dst = which ? Kh : Qh;

#pragma unroll
    for (int mf = 0; mf < 4; mf++) {
        float ss[4];
#pragma unroll
        for (int e = 0; e < 4; e++)
            ss[e] = acc[mf][0][e] * acc[mf][0][e] + acc[mf][1][e] * acc[mf][1][e]
                  + acc[mf][2][e] * acc[mf][2][e] + acc[mf][3][e] * acc[mf][3][e];
#pragma unroll
        for (int mask = 1; mask < 16; mask <<= 1)
#pragma unroll
            for (int e = 0; e < 4; e++)
                ss[e] += __shfl_xor(ss[e], mask);
        float inv[4];
#pragma unroll
        for (int e = 0; e < 4; e++) inv[e] = rsqrtf(ss[e] * (1.0f / 64.0f) + 1e-6f);

        float xn[4][4];
#pragma unroll
        for (int nf = 0; nf < 4; nf++)
#pragma unroll
            for (int e = 0; e < 4; e++)
                xn[nf][e] = acc[mf][nf][e] * inv[e] * gam[nf];

#pragma unroll
        for (int e = 0; e < 4; e++) {
            const int l = m0 + wm * 64 + mf * 16 + 4 * g + e;
            if (l < L) {
#pragma unroll
                for (int nf = 0; nf < 4; nf++) {
                    float ang = rope[(size_t)l * 64 + nf * 16 + r];
                    float sv, cv;
                    __sincosf(ang, &sv, &cv);
                    float rot = (nf < 2) ? -xn[nf + 2][e] : xn[nf - 2][e];
                    dst[(size_t)l * 1024 + hd * 64 + nf * 16 + r] =
                        (_Float16)((xn[nf][e] * cv + rot * sv) * qs);
                }
            } else if (which == 0) {
#pragma unroll
                for (int nf = 0; nf < 4; nf++)
                    dst[(size_t)l * 1024 + hd * 64 + nf * 16 + r] = (_Float16)0.f;
            }
        }
    }
}

// ---------------------------------------------------------------------------
// Out-projection GEMM, 64x128x32 tile, single f16 MFMA (A=AOf, B=Wof).
// ---------------------------------------------------------------------------
__global__ __launch_bounds__(256) void gemm_out_f16(
    const _Float16* __restrict__ Af, const _Float16* __restrict__ Bf,
    float* __restrict__ C)
{
    __shared__ _Float16 sA[64 * 32], sB[128 * 32];

    const int tid = threadIdx.x, lane = tid & 63, wv = tid >> 6;
    const int wm = wv >> 1, wn = wv & 1;
    const int r = lane & 15, g = lane >> 4;
    const int m0 = blockIdx.y * 64, n0 = blockIdx.x * 128;
    const int K = 1024;

    const int aar = tid >> 2, aac = ((tid & 3) ^ (aar & 3)) * 8;
    const size_t offA = (size_t)(m0 + aar) * K + aac;
    const int c0 = tid, c1 = tid + 256;
    const int br0 = c0 >> 2, bc0 = ((c0 & 3) ^ (br0 & 3)) * 8;
    const int br1 = c1 >> 2, bc1 = ((c1 & 3) ^ (br1 & 3)) * 8;
    const size_t offB0 = (size_t)(n0 + br0) * K + bc0;
    const size_t offB1 = (size_t)(n0 + br1) * K + bc1;
    const int dA = tid * 16, dB0 = tid * 16, dB1 = (tid + 256) * 16;

    f32x4 acc[2][4];
#pragma unroll
    for (int mf = 0; mf < 2; mf++)
#pragma unroll
        for (int nf = 0; nf < 4; nf++)
            acc[mf][nf] = (f32x4){0.f, 0.f, 0.f, 0.f};

    for (int kk = 0; kk < K; kk += 32) {
        __syncthreads();
        gld16((char*)sA + dA,  Af + offA + kk);
        gld16((char*)sB + dB0, Bf + offB0 + kk);
        gld16((char*)sB + dB1, Bf + offB1 + kk);
        __syncthreads();

        f16x8 fb[4];
#pragma unroll
        for (int nf = 0; nf < 4; nf++) {
            int row = wn * 64 + nf * 16 + r;
            fb[nf] = *(const f16x8*)((const char*)sB + row * 64 + ((g ^ (row & 3)) * 16));
        }
#pragma unroll
        for (int mf = 0; mf < 2; mf++) {
            int row = wm * 32 + mf * 16 + r;
            f16x8 fa = *(const f16x8*)((const char*)sA + row * 64 + ((g ^ (row & 3)) * 16));
#pragma unroll
            for (int nf = 0; nf < 4; nf++)
                acc[mf][nf] = __builtin_amdgcn_mfma_f32_16x16x32_f16(fa, fb[nf], acc[mf][nf], 0, 0, 0);
        }
    }

#pragma unroll
    for (int mf = 0; mf < 2; mf++)
#pragma unroll
        for (int nf = 0; nf < 4; nf++)
#pragma unroll
            for (int e = 0; e < 4; e++) {
                int row = m0 + wm * 32 + mf * 16 + 4 * g + e;
                int col = n0 + wn * 64 + nf * 16 + r;
                C[(size_t)row * 1024 + col] = acc[mf][nf][e];
            }
}

// ---------------------------------------------------------------------------
// Flash attention v12 = v11 with KV-split x4 (2432 blocks = 8 XCD x 304 =
// 2 heads/XCD). Each block handles 18-19 kv-tiles; scaled-f16 partial O.
// R9 showed flash is grid-depth-sensitive (halving cost +43%); deepen it.
// ---------------------------------------------------------------------------
__global__ __launch_bounds__(256) void flash12(
    const _Float16* __restrict__ Qh, const _Float16* __restrict__ Kh,
    const _Float16* __restrict__ Vt,
    _Float16* __restrict__ Oph, float* __restrict__ Lp, int L)
{
    __shared__ _Float16 KT[2][4096];
    __shared__ _Float16 VT[2][4096];

    const int tid = threadIdx.x, lane = tid & 63, wv = tid >> 6;
    const int r = lane & 31, g2 = lane >> 5;

    // 2432 = 8 * 304; idb contiguous within XCD -> 2 heads per XCD
    const int idb = (blockIdx.x & 7) * 304 + (blockIdx.x >> 3);
    const int h   = idb / 152;
    const int rem = idb % 152;
    const int s   = rem / 38;          // kv quarter 0..3
    const int qt  = rem % 38;
    const int q0  = qt * 128 + wv * 32;
    const int t0  = s * 19;
    const int nt  = (s == 3) ? 18 : 19;

    f16x8 qf[4];
#pragma unroll
    for (int kc = 0; kc < 4; kc++)
        qf[kc] = *(const f16x8*)(Qh + (size_t)(q0 + r) * 1024 + h * 64 + kc * 16 + g2 * 8);

    int loff[2][4];
#pragma unroll
    for (int blk = 0; blk < 2; blk++)
#pragma unroll
        for (int kc = 0; kc < 4; kc++)
            loff[blk][kc] = (blk * 32 + r) * 128 + (((2 * kc + g2) ^ (r & 7)) * 16);

    const int p0c = tid, p1c = 256 + tid;
    const int sr0 = p0c >> 3, sc0 = (p0c & 7) ^ (sr0 & 7);
    const int sr1 = p1c >> 3, sc1 = (p1c & 7) ^ (sr1 & 7);
    const _Float16* ksrc0 = Kh + (size_t)(t0 * 64 + sr0) * 1024 + h * 64 + sc0 * 8;
    const _Float16* ksrc1 = Kh + (size_t)(t0 * 64 + sr1) * 1024 + h * 64 + sc1 * 8;
    const _Float16* vsrc0 = Vt + (size_t)(h * 64 + sr0) * L + t0 * 64 + sc0 * 8;
    const _Float16* vsrc1 = Vt + (size_t)(h * 64 + sr1) * L + t0 * 64 + sc1 * 8;

#define STAGE(buf) do { \
        gld16((char*)&KT[buf][0] + wv * 1024,        ksrc0); \
        gld16((char*)&KT[buf][0] + 4096 + wv * 1024, ksrc1); \
        gld16((char*)&VT[buf][0] + wv * 1024,        vsrc0); \
        gld16((char*)&VT[buf][0] + 4096 + wv * 1024, vsrc1); \
        ksrc0 += 64 * 1024; ksrc1 += 64 * 1024; vsrc0 += 64; vsrc1 += 64; \
    } while (0)

    f32x16 o[2];
#pragma unroll
    for (int nb = 0; nb < 2; nb++)
#pragma unroll
        for (int e = 0; e < 16; e++) o[nb][e] = 0.f;
    float lsum0 = 0.f, lsum1 = 0.f;

    f32x16 z16;
#pragma unroll
    for (int e = 0; e < 16; e++) z16[e] = 0.f;
    const h2 ones2 = {(__fp16)1.0f, (__fp16)1.0f};

    STAGE(0);
    __syncthreads();

#define TILE(buf, dostage) do { \
        if (dostage) STAGE(buf ^ 1); \
        f32x16 sc_[2]; \
        __builtin_amdgcn_s_setprio(1); \
        _Pragma("unroll") \
        for (int mk = 0; mk < 2; mk++) { \
            f16x8 kf0 = *(const f16x8*)((const char*)&KT[buf][0] + loff[mk][0]); \
            sc_[mk] = __builtin_amdgcn_mfma_f32_32x32x16_f16(kf0, qf[0], z16, 0, 0, 0); \
            _Pragma("unroll") \
            for (int kc = 1; kc < 4; kc++) { \
                f16x8 kf = *(const f16x8*)((const char*)&KT[buf][0] + loff[mk][kc]); \
                sc_[mk] = __builtin_amdgcn_mfma_f32_32x32x16_f16(kf, qf[kc], sc_[mk], 0, 0, 0); \
            } \
        } \
        __builtin_amdgcn_s_setprio(0); \
        f16x8 pa[4]; \
        _Pragma("unroll") \
        for (int mk = 0; mk < 2; mk++) { \
            float ps[16]; \
            _Pragma("unroll") for (int e = 0; e < 16; e++) ps[e] = fexp2(sc_[mk][e]); \
            _Pragma("unroll") \
            for (int c = 0; c < 2; c++) { \
                unsigned a0 = pkrtz(ps[8 * c + 0], ps[8 * c + 1]); \
                unsigned a1 = pkrtz(ps[8 * c + 2], ps[8 * c + 3]); \
                unsigned b0 = pkrtz(ps[8 * c + 4], ps[8 * c + 5]); \
                unsigned b1 = pkrtz(ps[8 * c + 6], ps[8 * c + 7]); \
                half_exchange(a0, a1, b0, b1, g2); \
                lsum0 = __builtin_amdgcn_fdot2(__builtin_bit_cast(h2, a0), ones2, lsum0, false); \
                lsum0 = __builtin_amdgcn_fdot2(__builtin_bit_cast(h2, a1), ones2, lsum0, false); \
                lsum1 = __builtin_amdgcn_fdot2(__builtin_bit_cast(h2, b0), ones2, lsum1, false); \
                lsum1 = __builtin_amdgcn_fdot2(__builtin_bit_cast(h2, b1), ones2, lsum1, false); \
                uint4v fr = {a0, a1, b0, b1}; \
                pa[2 * mk + c] = __builtin_bit_cast(f16x8, fr); \
            } \
        } \
        __builtin_amdgcn_s_setprio(1); \
        _Pragma("unroll") \
        for (int nb = 0; nb < 2; nb++) \
            _Pragma("unroll") \
            for (int kc = 0; kc < 4; kc++) { \
                f16x8 vf = *(const f16x8*)((const char*)&VT[buf][0] + loff[nb][kc]); \
                o[nb] = __builtin_amdgcn_mfma_f32_32x32x16_f16(pa[kc], vf, o[nb], 0, 0, 0); \
            } \
        __builtin_amdgcn_s_setprio(0); \
        __syncthreads(); \
    } while (0)

    for (int t = 0; t + 2 < nt; t += 2) { TILE(0, true); TILE(1, true); }
    if (nt & 1) { TILE(0, false); }
    else        { TILE(0, true); TILE(1, false); }

#undef TILE
#undef STAGE

    // epilogue: partial l (f32) and scaled-f16 unnormalized partial O
    float lsum = lsum0 + lsum1;
    lsum += __shfl_xor(lsum, 32);
    if (g2 == 0 && q0 + r < 4800)
        Lp[(size_t)(s * 4800 + q0 + r) * 16 + h] = lsum;
#pragma unroll
    for (int reg = 0; reg < 16; reg++) {
        const int qrow = (reg & 3) + 8 * (reg >> 2) + 4 * g2;
        const int qg = q0 + qrow;
        if (qg < 4800) {
#pragma unroll
            for (int nb = 0; nb < 2; nb++)
                Oph[(size_t)(s * 4800 + qg) * 1024 + h * 64 + nb * 32 + r] =
                    (_Float16)(o[nb][reg] * 0.015625f);
        }
    }
}

// ---------------------------------------------------------------------------
// merge the four kv-quarter scaled-f16 partials, normalize (x64 unscale),
// emit f16 AO (out-proj A-operand).
// ---------------------------------------------------------------------------
__global__ __launch_bounds__(256) void merge_f16(
    const _Float16* __restrict__ Oph, const float* __restrict__ Lp,
    _Float16* __restrict__ AOf)
{
    const int q = blockIdx.x, t = threadIdx.x;
    const int d = t * 4, hh = d >> 6;
    f16x4 a = *(const f16x4*)(Oph + (size_t)q * 1024 + d);
    f16x4 b = *(const f16x4*)(Oph + (size_t)(4800 + q) * 1024 + d);
    f16x4 c = *(const f16x4*)(Oph + (size_t)(9600 + q) * 1024 + d);
    f16x4 e4 = *(const f16x4*)(Oph + (size_t)(14400 + q) * 1024 + d);
    const float l = Lp[(size_t)q * 16 + hh] + Lp[(size_t)(4800 + q) * 16 + hh]
                  + Lp[(size_t)(9600 + q) * 16 + hh] + Lp[(size_t)(14400 + q) * 16 + hh];
    const float inv = 64.0f / l;
    f16x4 v;
#pragma unroll
    for (int j = 0; j < 4; j++)
        v[j] = (_Float16)((((float)a[j] + (float)b[j]) + ((float)c[j] + (float)e4[j])) * inv);
    *(f16x4*)(AOf + (size_t)q * 1024 + d) = v;
}

// ---------------------------------------------------------------------------
extern "C" void kernel_launch(void* const* d_in, const int* in_sizes, int n_in,
                              void* d_out, int out_size, void* d_ws, size_t ws_size,
                              hipStream_t stream)
{
    const float* x    = (const float*)d_in[0];
    const float* rope = (const float*)d_in[1];
    const float* wq   = (const float*)d_in[2];
    const float* wk   = (const float*)d_in[3];
    const float* wv   = (const float*)d_in[4];
    const float* wo   = (const float*)d_in[5];
    const float* qg   = (const float*)d_in[6];
    const float* kg   = (const float*)d_in[7];
    float* out = (float*)d_out;

    const int L = 4800;
    char* ws = (char*)d_ws;

    // lifetime-packed workspace (peak 89.9 MB):
    //   [0, 39321600)           Oph  (f16 scaled partial O x4, flash output)
    //   [39321600, 40550400)    Lp   (4*4800*16 f32)
    //   [40550400, 42647552)    Wof (f16)      (live till final GEMM)
    //   [44130304, 54091776)    Qh (4864 rows f16)  -> dead after flash
    //   [54091776, 63922176)    Kh                  -> dead after flash
    //   [63922176, 73752576)    Vt
    //   [73752576, 83582976)    Xf   (f16)          -> dead after gemm_qkv
    //   [83582976, 89874432)    Wqkvf (f16)         -> dead after gemm_qkv
    //   [44130304, 53960704)    AOf (f16, merge output, aliases Qh)
    _Float16* Oph  = (_Float16*)ws;
    float* Lp      = (float*)(ws + 39321600);
    _Float16* Wof  = (_Float16*)(ws + 40550400);
    _Float16* Qh   = (_Float16*)(ws + 44130304);
    _Float16* Kh   = Qh + 4864 * 1024;
    _Float16* Vt   = Kh + 4800 * 1024;
    _Float16* Xf   = (_Float16*)(ws + 73752576);
    _Float16* Wqkvf= (_Float16*)(ws + 83582976);
    _Float16* AOf  = (_Float16*)(ws + 44130304); // alias Qh (dead at merge)

    split_all<<<4448, 256, 0, stream>>>(x, wq, wk, wv, wo, Xf, Wqkvf, Wof);
    gemm_qkv<<<dim3(24, 38), 256, 0, stream>>>(Xf, Wqkvf,
                                               rope, qg, kg, Qh, Kh, Vt);
    flash12<<<2432, 256, 0, stream>>>(Qh, Kh, Vt, Oph, Lp, L);
    merge_f16<<<4800, 256, 0, stream>>>(Oph, Lp, AOf);
    gemm_out_f16<<<dim3(8, 75), 256, 0, stream>>>(AOf, Wof, out);
}

// Round 17
// 221.223 us; speedup vs baseline: 1.0171x; 1.0171x over previous
//
#include <hip/hip_runtime.h>

typedef __attribute__((ext_vector_type(4)))  float    f32x4;
typedef __attribute__((ext_vector_type(16))) float    f32x16;
typedef __attribute__((ext_vector_type(8)))  short    bf16x8;
typedef __attribute__((ext_vector_type(8)))  _Float16 f16x8;
typedef __attribute__((ext_vector_type(4)))  _Float16 f16x4;
typedef __attribute__((ext_vector_type(4)))  unsigned uint4v;
typedef __fp16 h2 __attribute__((ext_vector_type(2)));

// ---------- helpers ----------
__device__ inline unsigned pkrtz(float a, float b) {
    auto v = __builtin_amdgcn_cvt_pkrtz(a, b);
    return __builtin_bit_cast(unsigned, v);
}
// raw v_exp_f32: safe here (|arg| <= 11.6 -> fully normal range, ~1 ULP)
__device__ inline float fexp2(float x) {
#if __has_builtin(__builtin_amdgcn_exp2f)
    return __builtin_amdgcn_exp2f(x);
#else
    return exp2f(x);
#endif
}
__device__ inline void gld16(void* lds, const void* g) {
    __builtin_amdgcn_global_load_lds(
        (const __attribute__((address_space(1))) void*)g,
        (__attribute__((address_space(3))) void*)lds, 16, 0, 0);
}

// half-exchange across the wave's 32-lane halves (hazard-safe builtin path;
// raw asm version produced sporadic stale reads in R6).
__device__ inline void half_exchange(unsigned& a0, unsigned& a1,
                                     unsigned& b0, unsigned& b1, int g2) {
#if __has_builtin(__builtin_amdgcn_permlane32_swap)
    {
        auto p = __builtin_amdgcn_permlane32_swap(a0, b0, false, false);
        a0 = p[0]; b0 = p[1];
        auto q = __builtin_amdgcn_permlane32_swap(a1, b1, false, false);
        a1 = q[0]; b1 = q[1];
    }
#else
    unsigned s0 = g2 ? a0 : b0, s1 = g2 ? a1 : b1;
    unsigned r0 = (unsigned)__shfl_xor((int)s0, 32);
    unsigned r1 = (unsigned)__shfl_xor((int)s1, 32);
    unsigned w0 = g2 ? r0 : a0, w1 = g2 ? r1 : a1;
    unsigned w2 = g2 ? b0 : r0, w3 = g2 ? b1 : r1;
    a0 = w0; a1 = w1; b0 = w2; b1 = w3;
#endif
}

// ---------------------------------------------------------------------------
// fused prep: x,wq,wk,wv,wo -> f16 (all GEMM inputs f16 single-MFMA).
// ---------------------------------------------------------------------------
__global__ __launch_bounds__(256) void split_all(
    const float* __restrict__ x,  const float* __restrict__ wq,
    const float* __restrict__ wk, const float* __restrict__ wv,
    const float* __restrict__ wo,
    _Float16* __restrict__ Xf, _Float16* __restrict__ Wqkvf,
    _Float16* __restrict__ Wof)
{
    const int b = blockIdx.x;
    const float* s; _Float16* d; int i;
    if (b < 2400)      { s = x;  d = Xf;                  i = b * 256 + threadIdx.x; }
    else if (b < 2912) { s = wq; d = Wqkvf;               i = (b - 2400) * 256 + threadIdx.x; }
    else if (b < 3424) { s = wk; d = Wqkvf + 1024 * 1024; i = (b - 2912) * 256 + threadIdx.x; }
    else if (b < 3936) { s = wv; d = Wqkvf + 2048 * 1024; i = (b - 3424) * 256 + threadIdx.x; }
    else               { s = wo; d = Wof;                 i = (b - 3936) * 256 + threadIdx.x; }

    f32x4 a = ((const f32x4*)s)[2 * i];
    f32x4 c = ((const f32x4*)s)[2 * i + 1];
    f16x8 v;
#pragma unroll
    for (int j = 0; j < 4; j++) { v[j] = (_Float16)a[j]; v[4 + j] = (_Float16)c[j]; }
    ((f16x8*)d)[i] = v;
}

// ---------------------------------------------------------------------------
// Fused QKV GEMM (128x128x32, single f16 MFMA) + RMSNorm/RoPE/f16 epilogue.
// 1-D grid 912 = 8 XCD x 114, bijectively XCD-chunked: each XCD owns ~4.75
// contiguous A-rows -> A panels become XCD-L2-resident (were fetched 8x).
// ---------------------------------------------------------------------------
__global__ __launch_bounds__(256) void gemm_qkv(
    const _Float16* __restrict__ Af, const _Float16* __restrict__ Bf,
    const float* __restrict__ rope,
    const float* __restrict__ qgam, const float* __restrict__ kgam,
    _Float16* __restrict__ Qh, _Float16* __restrict__ Kh,
    _Float16* __restrict__ Vt)
{
    __shared__ _Float16 sA[128 * 32], sB[128 * 32];

    const int tid = threadIdx.x, lane = tid & 63, wv = tid >> 6;
    const int wm = wv >> 1, wn = wv & 1;
    const int r = lane & 15, g = lane >> 4;
    const int lid = (blockIdx.x & 7) * 114 + (blockIdx.x >> 3); // 912 = 8*114
    const int m0 = (lid / 24) * 128, n0 = (lid % 24) * 128;
    const int K = 1024, L = 4800;

    const int c0 = tid, c1 = tid + 256;
    const int ar0 = c0 >> 2, ac0 = ((c0 & 3) ^ (ar0 & 3)) * 8;
    const int ar1 = c1 >> 2, ac1 = ((c1 & 3) ^ (ar1 & 3)) * 8;
    const size_t offA0 = (size_t)(m0 + ar0) * K + ac0;
    const size_t offA1 = (size_t)(m0 + ar1) * K + ac1;
    const size_t offB0 = (size_t)(n0 + ar0) * K + ac0;
    const size_t offB1 = (size_t)(n0 + ar1) * K + ac1;
    const int d0 = tid * 16, d1 = (tid + 256) * 16;

    f32x4 acc[4][4];
#pragma unroll
    for (int mf = 0; mf < 4; mf++)
#pragma unroll
        for (int nf = 0; nf < 4; nf++)
            acc[mf][nf] = (f32x4){0.f, 0.f, 0.f, 0.f};

    for (int kk = 0; kk < K; kk += 32) {
        __syncthreads();
        gld16((char*)sA + d0, Af + offA0 + kk);
        gld16((char*)sA + d1, Af + offA1 + kk);
        gld16((char*)sB + d0, Bf + offB0 + kk);
        gld16((char*)sB + d1, Bf + offB1 + kk);
        __syncthreads();

        f16x8 fb[4];
#pragma unroll
        for (int nf = 0; nf < 4; nf++) {
            int row = wn * 64 + nf * 16 + r;
            fb[nf] = *(const f16x8*)((const char*)sB + row * 64 + ((g ^ (row & 3)) * 16));
        }
#pragma unroll
        for (int mf = 0; mf < 4; mf++) {
            int row = wm * 64 + mf * 16 + r;
            f16x8 fa = *(const f16x8*)((const char*)sA + row * 64 + ((g ^ (row & 3)) * 16));
#pragma unroll
            for (int nf = 0; nf < 4; nf++)
                acc[mf][nf] = __builtin_amdgcn_mfma_f32_16x16x32_f16(fa, fb[nf], acc[mf][nf], 0, 0, 0);
        }
    }

    // ---------------- fused epilogue ----------------
    const int col0  = n0 + wn * 64;
    const int which = col0 >> 10;          // 0=Q 1=K 2=V
    const int hd    = (col0 & 1023) >> 6;  // head 0..15

    if (which == 2) {
#pragma unroll
        for (int mf = 0; mf < 4; mf++) {
            const int l0 = m0 + wm * 64 + mf * 16 + 4 * g;
            if (l0 < L) {
#pragma unroll
                for (int nf = 0; nf < 4; nf++) {
                    f16x4 v4;
#pragma unroll
                    for (int e = 0; e < 4; e++) v4[e] = (_Float16)acc[mf][nf][e];
                    *(f16x4*)(Vt + (size_t)(hd * 64 + nf * 16 + r) * L + l0) = v4;
                }
            }
        }
        return;
    }

    const float* G = which ? kgam : qgam;
    const float qs = which ? 1.0f : 0.18033688011112042f; // (1/8)*log2(e)
    float gam[4];
#pragma unroll
    for (int nf = 0; nf < 4; nf++) gam[nf] = G[nf * 16 + r];
    _Float16* dst = which ? Kh : Qh;

#pragma unroll
    for (int mf = 0; mf < 4; mf++) {
        float ss[4];
#pragma unroll
        for (int e = 0; e < 4; e++)
            ss[e] = acc[mf][0][e] * acc[mf][0][e] + acc[mf][1][e] * acc[mf][1][e]
                  + acc[mf][2][e] * acc[mf][2][e] + acc[mf][3][e] * acc[mf][3][e];
#pragma unroll
        for (int mask = 1; mask < 16; mask <<= 1)
#pragma unroll
            for (int e = 0; e < 4; e++)
                ss[e] += __shfl_xor(ss[e], mask);
        float inv[4];
#pragma unroll
        for (int e = 0; e < 4; e++) inv[e] = rsqrtf(ss[e] * (1.0f / 64.0f) + 1e-6f);

        float xn[4][4];
#pragma unroll
        for (int nf = 0; nf < 4; nf++)
#pragma unroll
            for (int e = 0; e < 4; e++)
                xn[nf][e] = acc[mf][nf][e] * inv[e] * gam[nf];

#pragma unroll
        for (int e = 0; e < 4; e++) {
            const int l = m0 + wm * 64 + mf * 16 + 4 * g + e;
            if (l < L) {
#pragma unroll
                for (int nf = 0; nf < 4; nf++) {
                    float ang = rope[(size_t)l * 64 + nf * 16 + r];
                    float sv, cv;
                    __sincosf(ang, &sv, &cv);
                    float rot = (nf < 2) ? -xn[nf + 2][e] : xn[nf - 2][e];
                    dst[(size_t)l * 1024 + hd * 64 + nf * 16 + r] =
                        (_Float16)((xn[nf][e] * cv + rot * sv) * qs);
                }
            } else if (which == 0) {
#pragma unroll
                for (int nf = 0; nf < 4; nf++)
                    dst[(size_t)l * 1024 + hd * 64 + nf * 16 + r] = (_Float16)0.f;
            }
        }
    }
}

// ---------------------------------------------------------------------------
// Out-projection GEMM, 64x128x32 tile, single f16 MFMA (A=AOf, B=Wof).
// 1-D grid 600 = 8 XCD x 75, bijectively XCD-chunked (contiguous m-rows
// per XCD -> A panel L2 reuse; Wof 2MB fits every L2).
// ---------------------------------------------------------------------------
__global__ __launch_bounds__(256) void gemm_out_f16(
    const _Float16* __restrict__ Af, const _Float16* __restrict__ Bf,
    float* __restrict__ C)
{
    __shared__ _Float16 sA[64 * 32], sB[128 * 32];

    const int tid = threadIdx.x, lane = tid & 63, wv = tid >> 6;
    const int wm = wv >> 1, wn = wv & 1;
    const int r = lane & 15, g = lane >> 4;
    const int lid = (blockIdx.x & 7) * 75 + (blockIdx.x >> 3); // 600 = 8*75
    const int m0 = (lid >> 3) * 64, n0 = (lid & 7) * 128;
    const int K = 1024;

    const int aar = tid >> 2, aac = ((tid & 3) ^ (aar & 3)) * 8;
    const size_t offA = (size_t)(m0 + aar) * K + aac;
    const int c0 = tid, c1 = tid + 256;
    const int br0 = c0 >> 2, bc0 = ((c0 & 3) ^ (br0 & 3)) * 8;
    const int br1 = c1 >> 2, bc1 = ((c1 & 3) ^ (br1 & 3)) * 8;
    const size_t offB0 = (size_t)(n0 + br0) * K + bc0;
    const size_t offB1 = (size_t)(n0 + br1) * K + bc1;
    const int dA = tid * 16, dB0 = tid * 16, dB1 = (tid + 256) * 16;

    f32x4 acc[2][4];
#pragma unroll
    for (int mf = 0; mf < 2; mf++)
#pragma unroll
        for (int nf = 0; nf < 4; nf++)
            acc[mf][nf] = (f32x4){0.f, 0.f, 0.f, 0.f};

    for (int kk = 0; kk < K; kk += 32) {
        __syncthreads();
        gld16((char*)sA + dA,  Af + offA + kk);
        gld16((char*)sB + dB0, Bf + offB0 + kk);
        gld16((char*)sB + dB1, Bf + offB1 + kk);
        __syncthreads();

        f16x8 fb[4];
#pragma unroll
        for (int nf = 0; nf < 4; nf++) {
            int row = wn * 64 + nf * 16 + r;
            fb[nf] = *(const f16x8*)((const char*)sB + row * 64 + ((g ^ (row & 3)) * 16));
        }
#pragma unroll
        for (int mf = 0; mf < 2; mf++) {
            int row = wm * 32 + mf * 16 + r;
            f16x8 fa = *(const f16x8*)((const char*)sA + row * 64 + ((g ^ (row & 3)) * 16));
#pragma unroll
            for (int nf = 0; nf < 4; nf++)
                acc[mf][nf] = __builtin_amdgcn_mfma_f32_16x16x32_f16(fa, fb[nf], acc[mf][nf], 0, 0, 0);
        }
    }

#pragma unroll
    for (int mf = 0; mf < 2; mf++)
#pragma unroll
        for (int nf = 0; nf < 4; nf++)
#pragma unroll
            for (int e = 0; e < 4; e++) {
                int row = m0 + wm * 32 + mf * 16 + 4 * g + e;
                int col = n0 + wn * 64 + nf * 16 + r;
                C[(size_t)row * 1024 + col] = acc[mf][nf][e];
            }
}

// ---------------------------------------------------------------------------
// Flash attention v11: KV-split x2 (1216 blocks — proven optimal depth;
// x4 in R16 gained nothing in-kernel and cost merge overhead).
// Scaled-f16 partial O (o * 2^-6; merge multiplies back by 64).
// ---------------------------------------------------------------------------
__global__ __launch_bounds__(256) void flash11(
    const _Float16* __restrict__ Qh, const _Float16* __restrict__ Kh,
    const _Float16* __restrict__ Vt,
    _Float16* __restrict__ Oph, float* __restrict__ Lp, int L)
{
    __shared__ _Float16 KT[2][4096];
    __shared__ _Float16 VT[2][4096];

    const int tid = threadIdx.x, lane = tid & 63, wv = tid >> 6;
    const int r = lane & 31, g2 = lane >> 5;

    const int li  = blockIdx.x >> 3;
    const int w   = (blockIdx.x & 7) * 152 + li;
    const int h   = w / 76;
    const int rem = w % 76;
    const int s   = rem / 38;
    const int qt  = rem % 38;
    const int q0  = qt * 128 + wv * 32;
    const int t0  = s * 38;
    const int nt  = s ? 37 : 38;

    f16x8 qf[4];
#pragma unroll
    for (int kc = 0; kc < 4; kc++)
        qf[kc] = *(const f16x8*)(Qh + (size_t)(q0 + r) * 1024 + h * 64 + kc * 16 + g2 * 8);

    int loff[2][4];
#pragma unroll
    for (int blk = 0; blk < 2; blk++)
#pragma unroll
        for (int kc = 0; kc < 4; kc++)
            loff[blk][kc] = (blk * 32 + r) * 128 + (((2 * kc + g2) ^ (r & 7)) * 16);

    const int p0c = tid, p1c = 256 + tid;
    const int sr0 = p0c >> 3, sc0 = (p0c & 7) ^ (sr0 & 7);
    const int sr1 = p1c >> 3, sc1 = (p1c & 7) ^ (sr1 & 7);
    const _Float16* ksrc0 = Kh + (size_t)(t0 * 64 + sr0) * 1024 + h * 64 + sc0 * 8;
    const _Float16* ksrc1 = Kh + (size_t)(t0 * 64 + sr1) * 1024 + h * 64 + sc1 * 8;
    const _Float16* vsrc0 = Vt + (size_t)(h * 64 + sr0) * L + t0 * 64 + sc0 * 8;
    const _Float16* vsrc1 = Vt + (size_t)(h * 64 + sr1) * L + t0 * 64 + sc1 * 8;

#define STAGE(buf) do { \
        gld16((char*)&KT[buf][0] + wv * 1024,        ksrc0); \
        gld16((char*)&KT[buf][0] + 4096 + wv * 1024, ksrc1); \
        gld16((char*)&VT[buf][0] + wv * 1024,        vsrc0); \
        gld16((char*)&VT[buf][0] + 4096 + wv * 1024, vsrc1); \
        ksrc0 += 64 * 1024; ksrc1 += 64 * 1024; vsrc0 += 64; vsrc1 += 64; \
    } while (0)

    f32x16 o[2];
#pragma unroll
    for (int nb = 0; nb < 2; nb++)
#pragma unroll
        for (int e = 0; e < 16; e++) o[nb][e] = 0.f;
    float lsum0 = 0.f, lsum1 = 0.f;

    f32x16 z16;
#pragma unroll
    for (int e = 0; e < 16; e++) z16[e] = 0.f;
    const h2 ones2 = {(__fp16)1.0f, (__fp16)1.0f};

    STAGE(0);
    __syncthreads();

#define TILE(buf, dostage) do { \
        if (dostage) STAGE(buf ^ 1); \
        f32x16 sc_[2]; \
        __builtin_amdgcn_s_setprio(1); \
        _Pragma("unroll") \
        for (int mk = 0; mk < 2; mk++) { \
            f16x8 kf0 = *(const f16x8*)((const char*)&KT[buf][0] + loff[mk][0]); \
            sc_[mk] = __builtin_amdgcn_mfma_f32_32x32x16_f16(kf0, qf[0], z16, 0, 0, 0); \
            _Pragma("unroll") \
            for (int kc = 1; kc < 4; kc++) { \
                f16x8 kf = *(const f16x8*)((const char*)&KT[buf][0] + loff[mk][kc]); \
                sc_[mk] = __builtin_amdgcn_mfma_f32_32x32x16_f16(kf, qf[kc], sc_[mk], 0, 0, 0); \
            } \
        } \
        __builtin_amdgcn_s_setprio(0); \
        f16x8 pa[4]; \
        _Pragma("unroll") \
        for (int mk = 0; mk < 2; mk++) { \
            float ps[16]; \
            _Pragma("unroll") for (int e = 0; e < 16; e++) ps[e] = fexp2(sc_[mk][e]); \
            _Pragma("unroll") \
            for (int c = 0; c < 2; c++) { \
                unsigned a0 = pkrtz(ps[8 * c + 0], ps[8 * c + 1]); \
                unsigned a1 = pkrtz(ps[8 * c + 2], ps[8 * c + 3]); \
                unsigned b0 = pkrtz(ps[8 * c + 4], ps[8 * c + 5]); \
                unsigned b1 = pkrtz(ps[8 * c + 6], ps[8 * c + 7]); \
                half_exchange(a0, a1, b0, b1, g2); \
                lsum0 = __builtin_amdgcn_fdot2(__builtin_bit_cast(h2, a0), ones2, lsum0, false); \
                lsum0 = __builtin_amdgcn_fdot2(__builtin_bit_cast(h2, a1), ones2, lsum0, false); \
                lsum1 = __builtin_amdgcn_fdot2(__builtin_bit_cast(h2, b0), ones2, lsum1, false); \
                lsum1 = __builtin_amdgcn_fdot2(__builtin_bit_cast(h2, b1), ones2, lsum1, false); \
                uint4v fr = {a0, a1, b0, b1}; \
                pa[2 * mk + c] = __builtin_bit_cast(f16x8, fr); \
            } \
        } \
        __builtin_amdgcn_s_setprio(1); \
        _Pragma("unroll") \
        for (int nb = 0; nb < 2; nb++) \
            _Pragma("unroll") \
            for (int kc = 0; kc < 4; kc++) { \
                f16x8 vf = *(const f16x8*)((const char*)&VT[buf][0] + loff[nb][kc]); \
                o[nb] = __builtin_amdgcn_mfma_f32_32x32x16_f16(pa[kc], vf, o[nb], 0, 0, 0); \
            } \
        __builtin_amdgcn_s_setprio(0); \
        __syncthreads(); \
    } while (0)

    for (int t = 0; t + 2 < nt; t += 2) { TILE(0, true); TILE(1, true); }
    if (s) { TILE(0, false); }
    else   { TILE(0, true); TILE(1, false); }

#undef TILE
#undef STAGE

    // epilogue: partial l (f32) and scaled-f16 unnormalized partial O
    float lsum = lsum0 + lsum1;
    lsum += __shfl_xor(lsum, 32);
    if (g2 == 0 && q0 + r < 4800)
        Lp[(size_t)(s * 4800 + q0 + r) * 16 + h] = lsum;
#pragma unroll
    for (int reg = 0; reg < 16; reg++) {
        const int qrow = (reg & 3) + 8 * (reg >> 2) + 4 * g2;
        const int qg = q0 + qrow;
        if (qg < 4800) {
#pragma unroll
            for (int nb = 0; nb < 2; nb++)
                Oph[(size_t)(s * 4800 + qg) * 1024 + h * 64 + nb * 32 + r] =
                    (_Float16)(o[nb][reg] * 0.015625f);
        }
    }
}

// ---------------------------------------------------------------------------
// merge the two kv-half scaled-f16 partials, normalize (x64 unscale),
// emit f16 AO (out-proj A-operand).
// ---------------------------------------------------------------------------
__global__ __launch_bounds__(256) void merge_f16(
    const _Float16* __restrict__ Oph, const float* __restrict__ Lp,
    _Float16* __restrict__ AOf)
{
    const int q = blockIdx.x, t = threadIdx.x;
    const int d = t * 4, hh = d >> 6;
    f16x4 a = *(const f16x4*)(Oph + (size_t)q * 1024 + d);
    f16x4 b = *(const f16x4*)(Oph + (size_t)(4800 + q) * 1024 + d);
    const float inv = 64.0f / (Lp[(size_t)q * 16 + hh] + Lp[(size_t)(4800 + q) * 16 + hh]);
    f16x4 v;
#pragma unroll
    for (int j = 0; j < 4; j++)
        v[j] = (_Float16)(((float)a[j] + (float)b[j]) * inv);
    *(f16x4*)(AOf + (size_t)q * 1024 + d) = v;
}

// ---------------------------------------------------------------------------
extern "C" void kernel_launch(void* const* d_in, const int* in_sizes, int n_in,
                              void* d_out, int out_size, void* d_ws, size_t ws_size,
                              hipStream_t stream)
{
    const float* x    = (const float*)d_in[0];
    const float* rope = (const float*)d_in[1];
    const float* wq   = (const float*)d_in[2];
    const float* wk   = (const float*)d_in[3];
    const float* wv   = (const float*)d_in[4];
    const float* wo   = (const float*)d_in[5];
    const float* qg   = (const float*)d_in[6];
    const float* kg   = (const float*)d_in[7];
    float* out = (float*)d_out;

    const int L = 4800;
    char* ws = (char*)d_ws;

    // lifetime-packed workspace (peak 89.9 MB):
    //   [0, 19660800)           Oph  (f16 scaled partial O x2, flash output)
    //   [39321600, 39936000)    Lp   (2*4800*16 f32)
    //   [39936000, 42033152)    Wof (f16)      (live till final GEMM)
    //   [44130304, 54091776)    Qh (4864 rows f16)  -> dead after flash
    //   [54091776, 63922176)    Kh                  -> dead after flash
    //   [63922176, 73752576)    Vt
    //   [73752576, 83582976)    Xf   (f16)          -> dead after gemm_qkv
    //   [83582976, 89874432)    Wqkvf (f16)         -> dead after gemm_qkv
    //   [44130304, 53960704)    AOf (f16, merge output, aliases Qh)
    _Float16* Oph  = (_Float16*)ws;
    float* Lp      = (float*)(ws + 39321600);
    _Float16* Wof  = (_Float16*)(ws + 39936000);
    _Float16* Qh   = (_Float16*)(ws + 44130304);
    _Float16* Kh   = Qh + 4864 * 1024;
    _Float16* Vt   = Kh + 4800 * 1024;
    _Float16* Xf   = (_Float16*)(ws + 73752576);
    _Float16* Wqkvf= (_Float16*)(ws + 83582976);
    _Float16* AOf  = (_Float16*)(ws + 44130304); // alias Qh (dead at merge)

    split_all<<<4448, 256, 0, stream>>>(x, wq, wk, wv, wo, Xf, Wqkvf, Wof);
    gemm_qkv<<<912, 256, 0, stream>>>(Xf, Wqkvf, rope, qg, kg, Qh, Kh, Vt);
    flash11<<<1216, 256, 0, stream>>>(Qh, Kh, Vt, Oph, Lp, L);
    merge_f16<<<4800, 256, 0, stream>>>(Oph, Lp, AOf);
    gemm_out_f16<<<600, 256, 0, stream>>>(AOf, Wof, out);
}

// Round 18
// 217.834 us; speedup vs baseline: 1.0329x; 1.0156x over previous
//
#include <hip/hip_runtime.h>

typedef __attribute__((ext_vector_type(4)))  float    f32x4;
typedef __attribute__((ext_vector_type(16))) float    f32x16;
typedef __attribute__((ext_vector_type(8)))  short    bf16x8;
typedef __attribute__((ext_vector_type(8)))  _Float16 f16x8;
typedef __attribute__((ext_vector_type(4)))  _Float16 f16x4;
typedef __attribute__((ext_vector_type(4)))  unsigned uint4v;
typedef __fp16 h2 __attribute__((ext_vector_type(2)));

// ---------- helpers ----------
__device__ inline unsigned pkrtz(float a, float b) {
    auto v = __builtin_amdgcn_cvt_pkrtz(a, b);
    return __builtin_bit_cast(unsigned, v);
}
// raw v_exp_f32: safe here (|arg| <= 11.6 -> fully normal range, ~1 ULP)
__device__ inline float fexp2(float x) {
#if __has_builtin(__builtin_amdgcn_exp2f)
    return __builtin_amdgcn_exp2f(x);
#else
    return exp2f(x);
#endif
}
__device__ inline void gld16(void* lds, const void* g) {
    __builtin_amdgcn_global_load_lds(
        (const __attribute__((address_space(1))) void*)g,
        (__attribute__((address_space(3))) void*)lds, 16, 0, 0);
}

// half-exchange across the wave's 32-lane halves (hazard-safe builtin path;
// raw asm version produced sporadic stale reads in R6).
__device__ inline void half_exchange(unsigned& a0, unsigned& a1,
                                     unsigned& b0, unsigned& b1, int g2) {
#if __has_builtin(__builtin_amdgcn_permlane32_swap)
    {
        auto p = __builtin_amdgcn_permlane32_swap(a0, b0, false, false);
        a0 = p[0]; b0 = p[1];
        auto q = __builtin_amdgcn_permlane32_swap(a1, b1, false, false);
        a1 = q[0]; b1 = q[1];
    }
#else
    unsigned s0 = g2 ? a0 : b0, s1 = g2 ? a1 : b1;
    unsigned r0 = (unsigned)__shfl_xor((int)s0, 32);
    unsigned r1 = (unsigned)__shfl_xor((int)s1, 32);
    unsigned w0 = g2 ? r0 : a0, w1 = g2 ? r1 : a1;
    unsigned w2 = g2 ? b0 : r0, w3 = g2 ? b1 : r1;
    a0 = w0; a1 = w1; b0 = w2; b1 = w3;
#endif
}

// ---------------------------------------------------------------------------
// fused prep: x,wq,wk,wv,wo -> f16 (all GEMM inputs f16 single-MFMA).
// ---------------------------------------------------------------------------
__global__ __launch_bounds__(256) void split_all(
    const float* __restrict__ x,  const float* __restrict__ wq,
    const float* __restrict__ wk, const float* __restrict__ wv,
    const float* __restrict__ wo,
    _Float16* __restrict__ Xf, _Float16* __restrict__ Wqkvf,
    _Float16* __restrict__ Wof)
{
    const int b = blockIdx.x;
    const float* s; _Float16* d; int i;
    if (b < 2400)      { s = x;  d = Xf;                  i = b * 256 + threadIdx.x; }
    else if (b < 2912) { s = wq; d = Wqkvf;               i = (b - 2400) * 256 + threadIdx.x; }
    else if (b < 3424) { s = wk; d = Wqkvf + 1024 * 1024; i = (b - 2912) * 256 + threadIdx.x; }
    else if (b < 3936) { s = wv; d = Wqkvf + 2048 * 1024; i = (b - 3424) * 256 + threadIdx.x; }
    else               { s = wo; d = Wof;                 i = (b - 3936) * 256 + threadIdx.x; }

    f32x4 a = ((const f32x4*)s)[2 * i];
    f32x4 c = ((const f32x4*)s)[2 * i + 1];
    f16x8 v;
#pragma unroll
    for (int j = 0; j < 4; j++) { v[j] = (_Float16)a[j]; v[4 + j] = (_Float16)c[j]; }
    ((f16x8*)d)[i] = v;
}

// ---------------------------------------------------------------------------
// Fused QKV GEMM (128x128, BK=64, single f16 MFMA) + RMSNorm/RoPE epilogue.
// BK=64: 16 k-iterations (was 32) -> half the vmcnt(0)+barrier drains,
// 32 MFMAs between barriers. LDS 2x16KB. 8-chunk/row XOR swizzle
// (chunk ^= row&7) applied on BOTH source and read (same involution).
// 1-D grid 912 = 8 XCD x 114, bijectively XCD-chunked.
// ---------------------------------------------------------------------------
__global__ __launch_bounds__(256) void gemm_qkv(
    const _Float16* __restrict__ Af, const _Float16* __restrict__ Bf,
    const float* __restrict__ rope,
    const float* __restrict__ qgam, const float* __restrict__ kgam,
    _Float16* __restrict__ Qh, _Float16* __restrict__ Kh,
    _Float16* __restrict__ Vt)
{
    __shared__ _Float16 sA[128 * 64], sB[128 * 64];

    const int tid = threadIdx.x, lane = tid & 63, wv = tid >> 6;
    const int wm = wv >> 1, wn = wv & 1;
    const int r = lane & 15, g = lane >> 4;
    const int lid = (blockIdx.x & 7) * 114 + (blockIdx.x >> 3); // 912 = 8*114
    const int m0 = (lid / 24) * 128, n0 = (lid % 24) * 128;
    const int K = 1024, L = 4800;

    // staging: per panel 128 rows x 8 chunks(16B) = 1024 chunks; 4/thread.
    // source col pre-swizzled: chunk c at row holds global chunk c^(row&7).
    int srow[4], scol[4];
#pragma unroll
    for (int p = 0; p < 4; p++) {
        int c = tid + 256 * p;
        srow[p] = c >> 3;
        scol[p] = ((c & 7) ^ (srow[p] & 7)) * 8;
    }

    f32x4 acc[4][4];
#pragma unroll
    for (int mf = 0; mf < 4; mf++)
#pragma unroll
        for (int nf = 0; nf < 4; nf++)
            acc[mf][nf] = (f32x4){0.f, 0.f, 0.f, 0.f};

    for (int kk = 0; kk < K; kk += 64) {
        __syncthreads();
#pragma unroll
        for (int p = 0; p < 4; p++) {
            const int db = (tid + 256 * p) * 16;
            gld16((char*)sA + db, Af + (size_t)(m0 + srow[p]) * K + kk + scol[p]);
            gld16((char*)sB + db, Bf + (size_t)(n0 + srow[p]) * K + kk + scol[p]);
        }
        __syncthreads();

        f16x8 fb[4][2];
#pragma unroll
        for (int nf = 0; nf < 4; nf++) {
            int row = wn * 64 + nf * 16 + r;
#pragma unroll
            for (int kc = 0; kc < 2; kc++)
                fb[nf][kc] = *(const f16x8*)((const char*)sB + row * 128 + (((kc * 4 + g) ^ (row & 7)) * 16));
        }
#pragma unroll
        for (int mf = 0; mf < 4; mf++) {
            int row = wm * 64 + mf * 16 + r;
            f16x8 fa0 = *(const f16x8*)((const char*)sA + row * 128 + (((g) ^ (row & 7)) * 16));
            f16x8 fa1 = *(const f16x8*)((const char*)sA + row * 128 + (((4 + g) ^ (row & 7)) * 16));
#pragma unroll
            for (int nf = 0; nf < 4; nf++) {
                acc[mf][nf] = __builtin_amdgcn_mfma_f32_16x16x32_f16(fa0, fb[nf][0], acc[mf][nf], 0, 0, 0);
                acc[mf][nf] = __builtin_amdgcn_mfma_f32_16x16x32_f16(fa1, fb[nf][1], acc[mf][nf], 0, 0, 0);
            }
        }
    }

    // ---------------- fused epilogue ----------------
    const int col0  = n0 + wn * 64;
    const int which = col0 >> 10;          // 0=Q 1=K 2=V
    const int hd    = (col0 & 1023) >> 6;  // head 0..15

    if (which == 2) {
#pragma unroll
        for (int mf = 0; mf < 4; mf++) {
            const int l0 = m0 + wm * 64 + mf * 16 + 4 * g;
            if (l0 < L) {
#pragma unroll
                for (int nf = 0; nf < 4; nf++) {
                    f16x4 v4;
#pragma unroll
                    for (int e = 0; e < 4; e++) v4[e] = (_Float16)acc[mf][nf][e];
                    *(f16x4*)(Vt + (size_t)(hd * 64 + nf * 16 + r) * L + l0) = v4;
                }
            }
        }
        return;
    }

    const float* G = which ? kgam : qgam;
    const float qs = which ? 1.0f : 0.18033688011112042f; // (1/8)*log2(e)
    float gam[4];
#pragma unroll
    for (int nf = 0; nf < 4; nf++) gam[nf] = G[nf * 16 + r];
    _Float16* dst = which ? Kh : Qh;

#pragma unroll
    for (int mf = 0; mf < 4; mf++) {
        float ss[4];
#pragma unroll
        for (int e = 0; e < 4; e++)
            ss[e] = acc[mf][0][e] * acc[mf][0][e] + acc[mf][1][e] * acc[mf][1][e]
                  + acc[mf][2][e] * acc[mf][2][e] + acc[mf][3][e] * acc[mf][3][e];
#pragma unroll
        for (int mask = 1; mask < 16; mask <<= 1)
#pragma unroll
            for (int e = 0; e < 4; e++)
                ss[e] += __shfl_xor(ss[e], mask);
        float inv[4];
#pragma unroll
        for (int e = 0; e < 4; e++) inv[e] = rsqrtf(ss[e] * (1.0f / 64.0f) + 1e-6f);

        float xn[4][4];
#pragma unroll
        for (int nf = 0; nf < 4; nf++)
#pragma unroll
            for (int e = 0; e < 4; e++)
                xn[nf][e] = acc[mf][nf][e] * inv[e] * gam[nf];

#pragma unroll
        for (int e = 0; e < 4; e++) {
            const int l = m0 + wm * 64 + mf * 16 + 4 * g + e;
            if (l < L) {
#pragma unroll
                for (int nf = 0; nf < 4; nf++) {
                    float ang = rope[(size_t)l * 64 + nf * 16 + r];
                    float sv, cv;
                    __sincosf(ang, &sv, &cv);
                    float rot = (nf < 2) ? -xn[nf + 2][e] : xn[nf - 2][e];
                    dst[(size_t)l * 1024 + hd * 64 + nf * 16 + r] =
                        (_Float16)((xn[nf][e] * cv + rot * sv) * qs);
                }
            } else if (which == 0) {
#pragma unroll
                for (int nf = 0; nf < 4; nf++)
                    dst[(size_t)l * 1024 + hd * 64 + nf * 16 + r] = (_Float16)0.f;
            }
        }
    }
}

// ---------------------------------------------------------------------------
// Out-projection GEMM, 64x128x32 tile, single f16 MFMA (A=AOf, B=Wof).
// 1-D grid 600 = 8 XCD x 75, bijectively XCD-chunked.
// ---------------------------------------------------------------------------
__global__ __launch_bounds__(256) void gemm_out_f16(
    const _Float16* __restrict__ Af, const _Float16* __restrict__ Bf,
    float* __restrict__ C)
{
    __shared__ _Float16 sA[64 * 32], sB[128 * 32];

    const int tid = threadIdx.x, lane = tid & 63, wv = tid >> 6;
    const int wm = wv >> 1, wn = wv & 1;
    const int r = lane & 15, g = lane >> 4;
    const int lid = (blockIdx.x & 7) * 75 + (blockIdx.x >> 3); // 600 = 8*75
    const int m0 = (lid >> 3) * 64, n0 = (lid & 7) * 128;
    const int K = 1024;

    const int aar = tid >> 2, aac = ((tid & 3) ^ (aar & 3)) * 8;
    const size_t offA = (size_t)(m0 + aar) * K + aac;
    const int c0 = tid, c1 = tid + 256;
    const int br0 = c0 >> 2, bc0 = ((c0 & 3) ^ (br0 & 3)) * 8;
    const int br1 = c1 >> 2, bc1 = ((c1 & 3) ^ (br1 & 3)) * 8;
    const size_t offB0 = (size_t)(n0 + br0) * K + bc0;
    const size_t offB1 = (size_t)(n0 + br1) * K + bc1;
    const int dA = tid * 16, dB0 = tid * 16, dB1 = (tid + 256) * 16;

    f32x4 acc[2][4];
#pragma unroll
    for (int mf = 0; mf < 2; mf++)
#pragma unroll
        for (int nf = 0; nf < 4; nf++)
            acc[mf][nf] = (f32x4){0.f, 0.f, 0.f, 0.f};

    for (int kk = 0; kk < K; kk += 32) {
        __syncthreads();
        gld16((char*)sA + dA,  Af + offA + kk);
        gld16((char*)sB + dB0, Bf + offB0 + kk);
        gld16((char*)sB + dB1, Bf + offB1 + kk);
        __syncthreads();

        f16x8 fb[4];
#pragma unroll
        for (int nf = 0; nf < 4; nf++) {
            int row = wn * 64 + nf * 16 + r;
            fb[nf] = *(const f16x8*)((const char*)sB + row * 64 + ((g ^ (row & 3)) * 16));
        }
#pragma unroll
        for (int mf = 0; mf < 2; mf++) {
            int row = wm * 32 + mf * 16 + r;
            f16x8 fa = *(const f16x8*)((const char*)sA + row * 64 + ((g ^ (row & 3)) * 16));
#pragma unroll
            for (int nf = 0; nf < 4; nf++)
                acc[mf][nf] = __builtin_amdgcn_mfma_f32_16x16x32_f16(fa, fb[nf], acc[mf][nf], 0, 0, 0);
        }
    }

#pragma unroll
    for (int mf = 0; mf < 2; mf++)
#pragma unroll
        for (int nf = 0; nf < 4; nf++)
#pragma unroll
            for (int e = 0; e < 4; e++) {
                int row = m0 + wm * 32 + mf * 16 + 4 * g + e;
                int col = n0 + wn * 64 + nf * 16 + r;
                C[(size_t)row * 1024 + col] = acc[mf][nf][e];
            }
}

// ---------------------------------------------------------------------------
// Flash attention v11: KV-split x2 (1216 blocks), scaled-f16 partial O.
// ---------------------------------------------------------------------------
__global__ __launch_bounds__(256) void flash11(
    const _Float16* __restrict__ Qh, const _Float16* __restrict__ Kh,
    const _Float16* __restrict__ Vt,
    _Float16* __restrict__ Oph, float* __restrict__ Lp, int L)
{
    __shared__ _Float16 KT[2][4096];
    __shared__ _Float16 VT[2][4096];

    const int tid = threadIdx.x, lane = tid & 63, wv = tid >> 6;
    const int r = lane & 31, g2 = lane >> 5;

    const int li  = blockIdx.x >> 3;
    const int w   = (blockIdx.x & 7) * 152 + li;
    const int h   = w / 76;
    const int rem = w % 76;
    const int s   = rem / 38;
    const int qt  = rem % 38;
    const int q0  = qt * 128 + wv * 32;
    const int t0  = s * 38;
    const int nt  = s ? 37 : 38;

    f16x8 qf[4];
#pragma unroll
    for (int kc = 0; kc < 4; kc++)
        qf[kc] = *(const f16x8*)(Qh + (size_t)(q0 + r) * 1024 + h * 64 + kc * 16 + g2 * 8);

    int loff[2][4];
#pragma unroll
    for (int blk = 0; blk < 2; blk++)
#pragma unroll
        for (int kc = 0; kc < 4; kc++)
            loff[blk][kc] = (blk * 32 + r) * 128 + (((2 * kc + g2) ^ (r & 7)) * 16);

    const int p0c = tid, p1c = 256 + tid;
    const int sr0 = p0c >> 3, sc0 = (p0c & 7) ^ (sr0 & 7);
    const int sr1 = p1c >> 3, sc1 = (p1c & 7) ^ (sr1 & 7);
    const _Float16* ksrc0 = Kh + (size_t)(t0 * 64 + sr0) * 1024 + h * 64 + sc0 * 8;
    const _Float16* ksrc1 = Kh + (size_t)(t0 * 64 + sr1) * 1024 + h * 64 + sc1 * 8;
    const _Float16* vsrc0 = Vt + (size_t)(h * 64 + sr0) * L + t0 * 64 + sc0 * 8;
    const _Float16* vsrc1 = Vt + (size_t)(h * 64 + sr1) * L + t0 * 64 + sc1 * 8;

#define STAGE(buf) do { \
        gld16((char*)&KT[buf][0] + wv * 1024,        ksrc0); \
        gld16((char*)&KT[buf][0] + 4096 + wv * 1024, ksrc1); \
        gld16((char*)&VT[buf][0] + wv * 1024,        vsrc0); \
        gld16((char*)&VT[buf][0] + 4096 + wv * 1024, vsrc1); \
        ksrc0 += 64 * 1024; ksrc1 += 64 * 1024; vsrc0 += 64; vsrc1 += 64; \
    } while (0)

    f32x16 o[2];
#pragma unroll
    for (int nb = 0; nb < 2; nb++)
#pragma unroll
        for (int e = 0; e < 16; e++) o[nb][e] = 0.f;
    float lsum0 = 0.f, lsum1 = 0.f;

    f32x16 z16;
#pragma unroll
    for (int e = 0; e < 16; e++) z16[e] = 0.f;
    const h2 ones2 = {(__fp16)1.0f, (__fp16)1.0f};

    STAGE(0);
    __syncthreads();

#define TILE(buf, dostage) do { \
        if (dostage) STAGE(buf ^ 1); \
        f32x16 sc_[2]; \
        __builtin_amdgcn_s_setprio(1); \
        _Pragma("unroll") \
        for (int mk = 0; mk < 2; mk++) { \
            f16x8 kf0 = *(const f16x8*)((const char*)&KT[buf][0] + loff[mk][0]); \
            sc_[mk] = __builtin_amdgcn_mfma_f32_32x32x16_f16(kf0, qf[0], z16, 0, 0, 0); \
            _Pragma("unroll") \
            for (int kc = 1; kc < 4; kc++) { \
                f16x8 kf = *(const f16x8*)((const char*)&KT[buf][0] + loff[mk][kc]); \
                sc_[mk] = __builtin_amdgcn_mfma_f32_32x32x16_f16(kf, qf[kc], sc_[mk], 0, 0, 0); \
            } \
        } \
        __builtin_amdgcn_s_setprio(0); \
        f16x8 pa[4]; \
        _Pragma("unroll") \
        for (int mk = 0; mk < 2; mk++) { \
            float ps[16]; \
            _Pragma("unroll") for (int e = 0; e < 16; e++) ps[e] = fexp2(sc_[mk][e]); \
            _Pragma("unroll") \
            for (int c = 0; c < 2; c++) { \
                unsigned a0 = pkrtz(ps[8 * c + 0], ps[8 * c + 1]); \
                unsigned a1 = pkrtz(ps[8 * c + 2], ps[8 * c + 3]); \
                unsigned b0 = pkrtz(ps[8 * c + 4], ps[8 * c + 5]); \
                unsigned b1 = pkrtz(ps[8 * c + 6], ps[8 * c + 7]); \
                half_exchange(a0, a1, b0, b1, g2); \
                lsum0 = __builtin_amdgcn_fdot2(__builtin_bit_cast(h2, a0), ones2, lsum0, false); \
                lsum0 = __builtin_amdgcn_fdot2(__builtin_bit_cast(h2, a1), ones2, lsum0, false); \
                lsum1 = __builtin_amdgcn_fdot2(__builtin_bit_cast(h2, b0), ones2, lsum1, false); \
                lsum1 = __builtin_amdgcn_fdot2(__builtin_bit_cast(h2, b1), ones2, lsum1, false); \
                uint4v fr = {a0, a1, b0, b1}; \
                pa[2 * mk + c] = __builtin_bit_cast(f16x8, fr); \
            } \
        } \
        __builtin_amdgcn_s_setprio(1); \
        _Pragma("unroll") \
        for (int nb = 0; nb < 2; nb++) \
            _Pragma("unroll") \
            for (int kc = 0; kc < 4; kc++) { \
                f16x8 vf = *(const f16x8*)((const char*)&VT[buf][0] + loff[nb][kc]); \
                o[nb] = __builtin_amdgcn_mfma_f32_32x32x16_f16(pa[kc], vf, o[nb], 0, 0, 0); \
            } \
        __builtin_amdgcn_s_setprio(0); \
        __syncthreads(); \
    } while (0)

    for (int t = 0; t + 2 < nt; t += 2) { TILE(0, true); TILE(1, true); }
    if (s) { TILE(0, false); }
    else   { TILE(0, true); TILE(1, false); }

#undef TILE
#undef STAGE

    // epilogue: partial l (f32) and scaled-f16 unnormalized partial O
    float lsum = lsum0 + lsum1;
    lsum += __shfl_xor(lsum, 32);
    if (g2 == 0 && q0 + r < 4800)
        Lp[(size_t)(s * 4800 + q0 + r) * 16 + h] = lsum;
#pragma unroll
    for (int reg = 0; reg < 16; reg++) {
        const int qrow = (reg & 3) + 8 * (reg >> 2) + 4 * g2;
        const int qg = q0 + qrow;
        if (qg < 4800) {
#pragma unroll
            for (int nb = 0; nb < 2; nb++)
                Oph[(size_t)(s * 4800 + qg) * 1024 + h * 64 + nb * 32 + r] =
                    (_Float16)(o[nb][reg] * 0.015625f);
        }
    }
}

// ---------------------------------------------------------------------------
// merge the two kv-half scaled-f16 partials, normalize (x64 unscale),
// emit f16 AO (out-proj A-operand).
// ---------------------------------------------------------------------------
__global__ __launch_bounds__(256) void merge_f16(
    const _Float16* __restrict__ Oph, const float* __restrict__ Lp,
    _Float16* __restrict__ AOf)
{
    const int q = blockIdx.x, t = threadIdx.x;
    const int d = t * 4, hh = d >> 6;
    f16x4 a = *(const f16x4*)(Oph + (size_t)q * 1024 + d);
    f16x4 b = *(const f16x4*)(Oph + (size_t)(4800 + q) * 1024 + d);
    const float inv = 64.0f / (Lp[(size_t)q * 16 + hh] + Lp[(size_t)(4800 + q) * 16 + hh]);
    f16x4 v;
#pragma unroll
    for (int j = 0; j < 4; j++)
        v[j] = (_Float16)(((float)a[j] + (float)b[j]) * inv);
    *(f16x4*)(AOf + (size_t)q * 1024 + d) = v;
}

// ---------------------------------------------------------------------------
extern "C" void kernel_launch(void* const* d_in, const int* in_sizes, int n_in,
                              void* d_out, int out_size, void* d_ws, size_t ws_size,
                              hipStream_t stream)
{
    const float* x    = (const float*)d_in[0];
    const float* rope = (const float*)d_in[1];
    const float* wq   = (const float*)d_in[2];
    const float* wk   = (const float*)d_in[3];
    const float* wv   = (const float*)d_in[4];
    const float* wo   = (const float*)d_in[5];
    const float* qg   = (const float*)d_in[6];
    const float* kg   = (const float*)d_in[7];
    float* out = (float*)d_out;

    const int L = 4800;
    char* ws = (char*)d_ws;

    _Float16* Oph  = (_Float16*)ws;
    float* Lp      = (float*)(ws + 39321600);
    _Float16* Wof  = (_Float16*)(ws + 39936000);
    _Float16* Qh   = (_Float16*)(ws + 44130304);
    _Float16* Kh   = Qh + 4864 * 1024;
    _Float16* Vt   = Kh + 4800 * 1024;
    _Float16* Xf   = (_Float16*)(ws + 73752576);
    _Float16* Wqkvf= (_Float16*)(ws + 83582976);
    _Float16* AOf  = (_Float16*)(ws + 44130304); // alias Qh (dead at merge)

    split_all<<<4448, 256, 0, stream>>>(x, wq, wk, wv, wo, Xf, Wqkvf, Wof);
    gemm_qkv<<<912, 256, 0, stream>>>(Xf, Wqkvf, rope, qg, kg, Qh, Kh, Vt);
    flash11<<<1216, 256, 0, stream>>>(Qh, Kh, Vt, Oph, Lp, L);
    merge_f16<<<4800, 256, 0, stream>>>(Oph, Lp, AOf);
    gemm_out_f16<<<600, 256, 0, stream>>>(AOf, Wof, out);
}